// Round 8
// baseline (551.681 us; speedup 1.0000x reference)
//
#include <hip/hip_runtime.h>
#include <hip/hip_fp16.h>

#define NN 100000
#define EE 1600000
#define IN_DIM 128
#define HID 64
#define NH 4
#define DH 16
#define NL 3
#define OUT_DIM 64
#define SLOPE 0.2f
#define LN_EPS 1e-5f
#define RB 4

// bucket CSR build
#define BSH 9
#define BSZ 512                               // nodes per bucket
#define NB ((NN + BSZ - 1) / BSZ)             // 196
#define CAP 10240                             // per-bucket capacity (avg 8163)
#define CHUNK 4096
#define P1_BLOCKS ((EE + CHUNK - 1) / CHUNK)  // 391

__device__ __forceinline__ float bcast(float x, int lane) {
    return __int_as_float(__builtin_amdgcn_readlane(__float_as_int(x), lane));
}
__device__ __forceinline__ unsigned f2bf(float x) {
    unsigned u = __float_as_uint(x);
    u += 0x7FFFu + ((u >> 16) & 1u);      // RNE
    return u >> 16;
}
__device__ __forceinline__ float bf2f(unsigned short b) {
    return __uint_as_float(((unsigned)b) << 16);
}

// h0 = X @ W_in + b_in. W column in registers.
__global__ __launch_bounds__(256, 2)
void k_in_gemm(const float* __restrict__ X, const float* __restrict__ W,
               const float* __restrict__ b, float* __restrict__ h) {
    const int j = threadIdx.x & 63;
    float Wreg[IN_DIM];
#pragma unroll
    for (int k = 0; k < IN_DIM; ++k) Wreg[k] = W[k * HID + j];
    const float bj = b[j];
    const int wid = (blockIdx.x * blockDim.x + threadIdx.x) >> 6;
    const int nw  = (gridDim.x * blockDim.x) >> 6;
    for (int v0 = wid * RB; v0 < NN; v0 += nw * RB) {
        float xlo[RB], xhi[RB];
#pragma unroll
        for (int r = 0; r < RB; ++r) {
            xlo[r] = X[(size_t)(v0 + r) * IN_DIM + j];
            xhi[r] = X[(size_t)(v0 + r) * IN_DIM + 64 + j];
        }
        float acc[RB];
#pragma unroll
        for (int r = 0; r < RB; ++r) acc[r] = bj;
#pragma unroll
        for (int k = 0; k < 64; ++k) {
#pragma unroll
            for (int r = 0; r < RB; ++r)
                acc[r] = fmaf(bcast(xlo[r], k), Wreg[k], acc[r]);
        }
#pragma unroll
        for (int k = 0; k < 64; ++k) {
#pragma unroll
            for (int r = 0; r < RB; ++r)
                acc[r] = fmaf(bcast(xhi[r], k), Wreg[64 + k], acc[r]);
        }
#pragma unroll
        for (int r = 0; r < RB; ++r) h[(size_t)(v0 + r) * HID + j] = acc[r];
    }
}

// z(bf16) = h @ W (64x64) + el/er head reductions. W column in registers.
__global__ __launch_bounds__(256, 4)
void k_zgemm(const float* __restrict__ h, const float* __restrict__ W,
             const float* __restrict__ al, const float* __restrict__ ar,
             unsigned* __restrict__ zb32,
             float* __restrict__ el, float* __restrict__ er) {
    const int j = threadIdx.x & 63;
    float Wreg[HID];
#pragma unroll
    for (int k = 0; k < HID; ++k) Wreg[k] = W[k * HID + j];
    const float alj = al[j];
    const float arj = ar[j];
    const int head = j >> 4;
    const int wid = (blockIdx.x * blockDim.x + threadIdx.x) >> 6;
    const int nw  = (gridDim.x * blockDim.x) >> 6;
    for (int v0 = wid * RB; v0 < NN; v0 += nw * RB) {
        float hv[RB];
#pragma unroll
        for (int r = 0; r < RB; ++r) hv[r] = h[(size_t)(v0 + r) * HID + j];
        float acc[RB];
#pragma unroll
        for (int r = 0; r < RB; ++r) acc[r] = 0.f;
#pragma unroll
        for (int k = 0; k < HID; ++k) {
#pragma unroll
            for (int r = 0; r < RB; ++r)
                acc[r] = fmaf(bcast(hv[r], k), Wreg[k], acc[r]);
        }
#pragma unroll
        for (int r = 0; r < RB; ++r) {
            const unsigned my = f2bf(acc[r]);
            const unsigned ot = (unsigned)__shfl_xor((int)my, 1, 64);
            if ((j & 1) == 0)
                zb32[(size_t)(v0 + r) * (HID / 2) + (j >> 1)] = my | (ot << 16);
            float pl = acc[r] * alj, pr = acc[r] * arj;
#pragma unroll
            for (int m = 8; m >= 1; m >>= 1) {
                pl += __shfl_xor(pl, m, 64);
                pr += __shfl_xor(pr, m, 64);
            }
            if ((j & 15) == 0) {
                el[(v0 + r) * NH + head] = pl;
                er[(v0 + r) * NH + head] = pr;
            }
        }
    }
}

// ---------------- bucket-sort CSR build ----------------

__global__ void k_zero_bcnt(int* __restrict__ bcnt) {
    if (threadIdx.x < NB) bcnt[threadIdx.x] = 0;
}

// Pass 1: block-local counting sort by bucket (d>>9), contiguous copy-out.
__global__ __launch_bounds__(256)
void k_bucketize(const int* __restrict__ src, const int* __restrict__ dst,
                 int* __restrict__ bcnt, int2* __restrict__ bbuf) {
    __shared__ int lh[256];      // hist -> running counter
    __shared__ int lbase[256];   // exclusive prefix
    __shared__ int lcnt[256];    // saved counts
    __shared__ int gbase[256];
    __shared__ int sc[256];
    __shared__ int2 stage[CHUNK];  // 32 KB
    const int t = threadIdx.x;
    const int e0 = blockIdx.x * CHUNK;
    const int n = min(CHUNK, EE - e0);
    lh[t] = 0;
    __syncthreads();
    int myd[CHUNK / 256], mys[CHUNK / 256];
#pragma unroll
    for (int i = 0; i < CHUNK / 256; ++i) {
        const int o = i * 256 + t;
        if (o < n) {
            myd[i] = dst[e0 + o];
            mys[i] = src[e0 + o];
            atomicAdd(&lh[myd[i] >> BSH], 1);
        } else myd[i] = -1;
    }
    __syncthreads();
    {   // exclusive scan of lh
        const int v = lh[t];
        lcnt[t] = v;
        sc[t] = v;
        __syncthreads();
        for (int off = 1; off < 256; off <<= 1) {
            const int x = (t >= off) ? sc[t - off] : 0;
            __syncthreads();
            sc[t] += x;
            __syncthreads();
        }
        lbase[t] = sc[t] - v;
        lh[t] = sc[t] - v;     // running counter
    }
    __syncthreads();
#pragma unroll
    for (int i = 0; i < CHUNK / 256; ++i) {
        if (myd[i] >= 0) {
            const int b = myd[i] >> BSH;
            const int p = atomicAdd(&lh[b], 1);
            stage[p] = make_int2(mys[i], myd[i]);
        }
    }
    __syncthreads();
    if (t < NB && lcnt[t] > 0) gbase[t] = atomicAdd(&bcnt[t], lcnt[t]);
    __syncthreads();
    for (int i = t; i < n; i += 256) {
        const int2 en = stage[i];
        const int b = en.y >> BSH;
        const int gp = gbase[b] + (i - lbase[b]);
        if (gp < CAP) bbuf[(size_t)b * CAP + gp] = en;
    }
}

// Pass 1.5: exclusive scan of the 196 bucket counts.
__global__ void k_bscan(const int* __restrict__ bcnt, int* __restrict__ bbase,
                        int* __restrict__ rowptr) {
    const int t = threadIdx.x;
    __shared__ int sc[256];
    const int v = (t < NB) ? bcnt[t] : 0;
    sc[t] = v;
    __syncthreads();
    for (int off = 1; off < 256; off <<= 1) {
        const int x = (t >= off) ? sc[t - off] : 0;
        __syncthreads();
        sc[t] += x;
        __syncthreads();
    }
    if (t < NB) bbase[t] = sc[t] - v;
    if (t == 0) rowptr[NN] = EE;
}

// Pass 2: one block per bucket — local hist+scan over 512 nodes,
// coalesced rowptr write, esrc/edst scatter confined to this block's region.
__global__ __launch_bounds__(256)
void k_localcsr(const int* __restrict__ bcnt, const int* __restrict__ bbase,
                const int2* __restrict__ bbuf, int* __restrict__ rowptr,
                int* __restrict__ esrc, int* __restrict__ edst) {
    const int b = blockIdx.x;
    const int t = threadIdx.x;
    const int cnt = bcnt[b];
    const int base = bbase[b];
    const int n0 = b * BSZ;
    const int nn = min(BSZ, NN - n0);
    __shared__ int lh[BSZ];
    __shared__ int lsc[BSZ];
    __shared__ int sc[256];
    for (int i = t; i < BSZ; i += 256) lh[i] = 0;
    __syncthreads();
    const int2* bb = bbuf + (size_t)b * CAP;
    for (int i = t; i < cnt; i += 256) atomicAdd(&lh[bb[i].y & (BSZ - 1)], 1);
    __syncthreads();
    const int a0 = lh[2 * t], a1 = lh[2 * t + 1];
    const int ts = a0 + a1;
    sc[t] = ts;
    __syncthreads();
    for (int off = 1; off < 256; off <<= 1) {
        const int x = (t >= off) ? sc[t - off] : 0;
        __syncthreads();
        sc[t] += x;
        __syncthreads();
    }
    const int ebase = sc[t] - ts;
    lsc[2 * t] = ebase;
    lsc[2 * t + 1] = ebase + a0;
    __syncthreads();
    for (int i = t; i < BSZ; i += 256) {
        if (i < nn) rowptr[n0 + i] = base + lsc[i];
        lh[i] = lsc[i];        // running counters
    }
    __syncthreads();
    for (int i = t; i < cnt; i += 256) {
        const int2 en = bb[i];
        const int p = atomicAdd(&lh[en.y & (BSZ - 1)], 1);
        esrc[base + p] = en.x;
        edst[base + p] = en.y;
    }
}

// ---------------- per-edge attention weights (per layer) ----------------
// w[h] = exp(leakyrelu(el[s][h] + er[d][h])), stored fp16 in 4 head-planes.
__global__ __launch_bounds__(256)
void k_wcalc(const int* __restrict__ esrc, const int* __restrict__ edst,
             const float* __restrict__ el, const float* __restrict__ er,
             __half* __restrict__ wpl) {
    const int i = blockIdx.x * 256 + threadIdx.x;
    if (i >= EE) return;
    const int s = esrc[i], d = edst[i];
    const float4 l4 = *(const float4*)(el + (size_t)s * NH);
    const float4 r4 = *(const float4*)(er + (size_t)d * NH);
    float x0 = l4.x + r4.x, x1 = l4.y + r4.y, x2 = l4.z + r4.z, x3 = l4.w + r4.w;
    const float w0 = __expf(fmaxf(x0, SLOPE * x0));
    const float w1 = __expf(fmaxf(x1, SLOPE * x1));
    const float w2 = __expf(fmaxf(x2, SLOPE * x2));
    const float w3 = __expf(fmaxf(x3, SLOPE * x3));
    wpl[0 * (size_t)EE + i] = __float2half_rn(w0);
    wpl[1 * (size_t)EE + i] = __float2half_rn(w1);
    wpl[2 * (size_t)EE + i] = __float2half_rn(w2);
    wpl[3 * (size_t)EE + i] = __float2half_rn(w3);
}

// ---------------- fused per-dst GAT aggregation (weights precomputed) ----------------
__global__ void k_gat_dst(const int* __restrict__ rowptr, const int* __restrict__ esrc,
                          const __half* __restrict__ wpl,
                          const unsigned short* __restrict__ zb, const float* __restrict__ hin,
                          const float* __restrict__ bg, float* __restrict__ hout) {
    const unsigned j = threadIdx.x & 63;
    const int wv = threadIdx.x >> 6;
    const int hh = j >> 4;
    const int d = blockIdx.x * 4 + wv;
    if (d >= NN) return;
    const int r0 = rowptr[d], r1 = rowptr[d + 1];
    const __half* wp = wpl + (size_t)hh * EE;
    float den = 0.f, sum = 0.f;
    int i = r0;
    // align i to 4 for vector loads
    for (; i < r1 && (i & 3); ++i) {
        const unsigned s = (unsigned)esrc[i];
        const float w = __half2float(wp[i]);
        den += w;
        sum += w * bf2f(zb[(s << 6) + j]);
    }
    for (; i + 8 <= r1; i += 8) {
        const int4 sa = *(const int4*)(esrc + i);
        const int4 sb = *(const int4*)(esrc + i + 4);
        const __half2 wh0 = *(const __half2*)(wp + i);
        const __half2 wh1 = *(const __half2*)(wp + i + 2);
        const __half2 wh2 = *(const __half2*)(wp + i + 4);
        const __half2 wh3 = *(const __half2*)(wp + i + 6);
        float zz[8];
        zz[0] = bf2f(zb[(((unsigned)sa.x) << 6) + j]);
        zz[1] = bf2f(zb[(((unsigned)sa.y) << 6) + j]);
        zz[2] = bf2f(zb[(((unsigned)sa.z) << 6) + j]);
        zz[3] = bf2f(zb[(((unsigned)sa.w) << 6) + j]);
        zz[4] = bf2f(zb[(((unsigned)sb.x) << 6) + j]);
        zz[5] = bf2f(zb[(((unsigned)sb.y) << 6) + j]);
        zz[6] = bf2f(zb[(((unsigned)sb.z) << 6) + j]);
        zz[7] = bf2f(zb[(((unsigned)sb.w) << 6) + j]);
        const float2 f0 = __half22float2(wh0);
        const float2 f1 = __half22float2(wh1);
        const float2 f2 = __half22float2(wh2);
        const float2 f3 = __half22float2(wh3);
        den += ((f0.x + f0.y) + (f1.x + f1.y)) + ((f2.x + f2.y) + (f3.x + f3.y));
        sum += f0.x * zz[0] + f0.y * zz[1] + f1.x * zz[2] + f1.y * zz[3]
             + f2.x * zz[4] + f2.y * zz[5] + f3.x * zz[6] + f3.y * zz[7];
    }
    for (; i < r1; ++i) {
        const unsigned s = (unsigned)esrc[i];
        const float w = __half2float(wp[i]);
        den += w;
        sum += w * bf2f(zb[(s << 6) + j]);
    }
    float o = hin[(size_t)d * HID + j] + bg[j];
    if (r1 > r0 && den > 0.f) o += sum / den;
    hout[(size_t)d * HID + j] = o;
}

// LayerNorm + out = hn @ W_out + b_out. W column in registers.
__global__ __launch_bounds__(256, 4)
void k_ln_out(const float* __restrict__ h, const float* __restrict__ g,
              const float* __restrict__ be, const float* __restrict__ Wo,
              const float* __restrict__ bo, float* __restrict__ out) {
    const int j = threadIdx.x & 63;
    float Wreg[HID];
#pragma unroll
    for (int k = 0; k < HID; ++k) Wreg[k] = Wo[k * OUT_DIM + j];
    const float gj = g[j], bej = be[j], boj = bo[j];
    const int wid = (blockIdx.x * blockDim.x + threadIdx.x) >> 6;
    const int nw  = (gridDim.x * blockDim.x) >> 6;
    for (int v0 = wid * RB; v0 < NN; v0 += nw * RB) {
        float hn[RB];
#pragma unroll
        for (int r = 0; r < RB; ++r) {
            const float x = h[(size_t)(v0 + r) * HID + j];
            float s = x;
#pragma unroll
            for (int m = 32; m >= 1; m >>= 1) s += __shfl_xor(s, m, 64);
            const float mu = s * (1.f / 64.f);
            const float dx = x - mu;
            float vs = dx * dx;
#pragma unroll
            for (int m = 32; m >= 1; m >>= 1) vs += __shfl_xor(vs, m, 64);
            hn[r] = dx * rsqrtf(vs * (1.f / 64.f) + LN_EPS) * gj + bej;
        }
        float acc[RB];
#pragma unroll
        for (int r = 0; r < RB; ++r) acc[r] = boj;
#pragma unroll
        for (int k = 0; k < HID; ++k) {
#pragma unroll
            for (int r = 0; r < RB; ++r)
                acc[r] = fmaf(bcast(hn[r], k), Wreg[k], acc[r]);
        }
#pragma unroll
        for (int r = 0; r < RB; ++r) out[(size_t)(v0 + r) * OUT_DIM + j] = acc[r];
    }
}

extern "C" void kernel_launch(void* const* d_in, const int* in_sizes, int n_in,
                              void* d_out, int out_size, void* d_ws, size_t ws_size,
                              hipStream_t stream) {
    const float* X     = (const float*)d_in[0];
    const int*   src   = (const int*)d_in[1];
    const int*   dst   = (const int*)d_in[2];
    const float* W_in  = (const float*)d_in[3];
    const float* b_in  = (const float*)d_in[4];
    // d_in[5..8]: rewiring MLP params — output is dead, skipped entirely
    const float* W_gat = (const float*)d_in[9];   // (L,64,64)
    const float* a_l   = (const float*)d_in[10];  // (L,4,16)
    const float* a_r   = (const float*)d_in[11];
    const float* b_gat = (const float*)d_in[12];  // (L,64)
    const float* ln_g  = (const float*)d_in[13];
    const float* ln_b  = (const float*)d_in[14];
    const float* W_out = (const float*)d_in[15];
    const float* b_out = (const float*)d_in[16];
    float* out = (float*)d_out;

    float* ws = (float*)d_ws;
    float* hA = ws;                                   // N*64 f32
    float* hB = hA + (size_t)NN * HID;                // N*64 f32
    unsigned short* zb = (unsigned short*)(hB + (size_t)NN * HID);  // N*64 bf16
    float* el = (float*)(zb + (size_t)NN * HID);      // N*4
    float* er = el + (size_t)NN * NH;                 // N*4
    int* rowptr = (int*)(er + (size_t)NN * NH);       // N+1 ints
    int* esrc   = rowptr + NN + 1;                    // E ints
    int* bcnt   = esrc + EE;                          // NB ints
    int* bbase  = bcnt + NB;                          // NB ints
    int2* bbuf  = (int2*)hB;  // 16.1 MB, aliases hB (dead until first k_gat_dst)

    // d_out doubles as scratch until k_ln_out overwrites it at the end:
    int* edst    = (int*)d_out;                               // E ints (6.4 MB)
    __half* wpl  = (__half*)((char*)d_out + (size_t)EE * 4);  // 4 planes x E fp16 (12.8 MB)

    k_in_gemm<<<1024, 256, 0, stream>>>(X, W_in, b_in, hA);

    // bucket-sort CSR by dst (built once, reused for all 3 layers)
    k_zero_bcnt<<<1, 256, 0, stream>>>(bcnt);
    k_bucketize<<<P1_BLOCKS, 256, 0, stream>>>(src, dst, bcnt, bbuf);
    k_bscan<<<1, 256, 0, stream>>>(bcnt, bbase, rowptr);
    k_localcsr<<<NB, 256, 0, stream>>>(bcnt, bbase, bbuf, rowptr, esrc, edst);

    float* hin = hA;
    float* hout = hB;
    for (int l = 0; l < NL; ++l) {
        k_zgemm<<<1024, 256, 0, stream>>>(hin, W_gat + (size_t)l * HID * HID,
                                          a_l + (size_t)l * HID, a_r + (size_t)l * HID,
                                          (unsigned*)zb, el, er);
        k_wcalc<<<EE / 256, 256, 0, stream>>>(esrc, edst, el, er, wpl);
        k_gat_dst<<<(NN + 3) / 4, 256, 0, stream>>>(rowptr, esrc, wpl, zb, hin,
                                                    b_gat + (size_t)l * HID, hout);
        float* t = hin; hin = hout; hout = t;
    }

    k_ln_out<<<1024, 256, 0, stream>>>(hin, ln_g, ln_b, W_out, b_out, out);
}

// Round 9
// 438.378 us; speedup vs baseline: 1.2585x; 1.2585x over previous
//
#include <hip/hip_runtime.h>

#define NN 100000
#define EE 1600000
#define IN_DIM 128
#define HID 64
#define NH 4
#define DH 16
#define NL 3
#define OUT_DIM 64
#define SLOPE 0.2f
#define LN_EPS 1e-5f
#define RB 4

// bucket CSR build
#define BSH 9
#define BSZ 512                               // nodes per bucket
#define NB ((NN + BSZ - 1) / BSZ)             // 196
#define CAP 10240                             // per-bucket capacity (avg 8163)
#define CHUNK 4096
#define P1_BLOCKS ((EE + CHUNK - 1) / CHUNK)  // 391

__device__ __forceinline__ float bcast(float x, int lane) {
    return __int_as_float(__builtin_amdgcn_readlane(__float_as_int(x), lane));
}
__device__ __forceinline__ unsigned f2bf(float x) {
    unsigned u = __float_as_uint(x);
    u += 0x7FFFu + ((u >> 16) & 1u);      // RNE
    return u >> 16;
}
__device__ __forceinline__ float bflo(unsigned zp) {   // low bf16 of dword
    return __uint_as_float(zp << 16);
}
__device__ __forceinline__ float bfhi(unsigned zp) {   // high bf16 of dword
    return __uint_as_float(zp & 0xFFFF0000u);
}

// h0 = X @ W_in + b_in. W column in registers.
__global__ __launch_bounds__(256, 2)
void k_in_gemm(const float* __restrict__ X, const float* __restrict__ W,
               const float* __restrict__ b, float* __restrict__ h) {
    const int j = threadIdx.x & 63;
    float Wreg[IN_DIM];
#pragma unroll
    for (int k = 0; k < IN_DIM; ++k) Wreg[k] = W[k * HID + j];
    const float bj = b[j];
    const int wid = (blockIdx.x * blockDim.x + threadIdx.x) >> 6;
    const int nw  = (gridDim.x * blockDim.x) >> 6;
    for (int v0 = wid * RB; v0 < NN; v0 += nw * RB) {
        float xlo[RB], xhi[RB];
#pragma unroll
        for (int r = 0; r < RB; ++r) {
            xlo[r] = X[(size_t)(v0 + r) * IN_DIM + j];
            xhi[r] = X[(size_t)(v0 + r) * IN_DIM + 64 + j];
        }
        float acc[RB];
#pragma unroll
        for (int r = 0; r < RB; ++r) acc[r] = bj;
#pragma unroll
        for (int k = 0; k < 64; ++k) {
#pragma unroll
            for (int r = 0; r < RB; ++r)
                acc[r] = fmaf(bcast(xlo[r], k), Wreg[k], acc[r]);
        }
#pragma unroll
        for (int k = 0; k < 64; ++k) {
#pragma unroll
            for (int r = 0; r < RB; ++r)
                acc[r] = fmaf(bcast(xhi[r], k), Wreg[64 + k], acc[r]);
        }
#pragma unroll
        for (int r = 0; r < RB; ++r) h[(size_t)(v0 + r) * HID + j] = acc[r];
    }
}

// z(bf16) = h @ W (64x64) + el/er head reductions. W column in registers.
__global__ __launch_bounds__(256, 4)
void k_zgemm(const float* __restrict__ h, const float* __restrict__ W,
             const float* __restrict__ al, const float* __restrict__ ar,
             unsigned* __restrict__ zb32,
             float* __restrict__ el, float* __restrict__ er) {
    const int j = threadIdx.x & 63;
    float Wreg[HID];
#pragma unroll
    for (int k = 0; k < HID; ++k) Wreg[k] = W[k * HID + j];
    const float alj = al[j];
    const float arj = ar[j];
    const int head = j >> 4;
    const int wid = (blockIdx.x * blockDim.x + threadIdx.x) >> 6;
    const int nw  = (gridDim.x * blockDim.x) >> 6;
    for (int v0 = wid * RB; v0 < NN; v0 += nw * RB) {
        float hv[RB];
#pragma unroll
        for (int r = 0; r < RB; ++r) hv[r] = h[(size_t)(v0 + r) * HID + j];
        float acc[RB];
#pragma unroll
        for (int r = 0; r < RB; ++r) acc[r] = 0.f;
#pragma unroll
        for (int k = 0; k < HID; ++k) {
#pragma unroll
            for (int r = 0; r < RB; ++r)
                acc[r] = fmaf(bcast(hv[r], k), Wreg[k], acc[r]);
        }
#pragma unroll
        for (int r = 0; r < RB; ++r) {
            const unsigned my = f2bf(acc[r]);
            const unsigned ot = (unsigned)__shfl_xor((int)my, 1, 64);
            if ((j & 1) == 0)
                zb32[(size_t)(v0 + r) * (HID / 2) + (j >> 1)] = my | (ot << 16);
            float pl = acc[r] * alj, pr = acc[r] * arj;
#pragma unroll
            for (int m = 8; m >= 1; m >>= 1) {
                pl += __shfl_xor(pl, m, 64);
                pr += __shfl_xor(pr, m, 64);
            }
            if ((j & 15) == 0) {
                el[(v0 + r) * NH + head] = pl;
                er[(v0 + r) * NH + head] = pr;
            }
        }
    }
}

// ---------------- bucket-sort CSR build ----------------

__global__ void k_zero_bcnt(int* __restrict__ bcnt) {
    if (threadIdx.x < NB) bcnt[threadIdx.x] = 0;
}

// Pass 1: block-local counting sort by bucket (d>>9), contiguous copy-out.
__global__ __launch_bounds__(256)
void k_bucketize(const int* __restrict__ src, const int* __restrict__ dst,
                 int* __restrict__ bcnt, int2* __restrict__ bbuf) {
    __shared__ int lh[256];      // hist -> running counter
    __shared__ int lbase[256];   // exclusive prefix
    __shared__ int lcnt[256];    // saved counts
    __shared__ int gbase[256];
    __shared__ int sc[256];
    __shared__ int2 stage[CHUNK];  // 32 KB
    const int t = threadIdx.x;
    const int e0 = blockIdx.x * CHUNK;
    const int n = min(CHUNK, EE - e0);
    lh[t] = 0;
    __syncthreads();
    int myd[CHUNK / 256], mys[CHUNK / 256];
#pragma unroll
    for (int i = 0; i < CHUNK / 256; ++i) {
        const int o = i * 256 + t;
        if (o < n) {
            myd[i] = dst[e0 + o];
            mys[i] = src[e0 + o];
            atomicAdd(&lh[myd[i] >> BSH], 1);
        } else myd[i] = -1;
    }
    __syncthreads();
    {   // exclusive scan of lh
        const int v = lh[t];
        lcnt[t] = v;
        sc[t] = v;
        __syncthreads();
        for (int off = 1; off < 256; off <<= 1) {
            const int x = (t >= off) ? sc[t - off] : 0;
            __syncthreads();
            sc[t] += x;
            __syncthreads();
        }
        lbase[t] = sc[t] - v;
        lh[t] = sc[t] - v;     // running counter
    }
    __syncthreads();
#pragma unroll
    for (int i = 0; i < CHUNK / 256; ++i) {
        if (myd[i] >= 0) {
            const int b = myd[i] >> BSH;
            const int p = atomicAdd(&lh[b], 1);
            stage[p] = make_int2(mys[i], myd[i]);
        }
    }
    __syncthreads();
    if (t < NB && lcnt[t] > 0) gbase[t] = atomicAdd(&bcnt[t], lcnt[t]);
    __syncthreads();
    for (int i = t; i < n; i += 256) {
        const int2 en = stage[i];
        const int b = en.y >> BSH;
        const int gp = gbase[b] + (i - lbase[b]);
        if (gp < CAP) bbuf[(size_t)b * CAP + gp] = en;
    }
}

// Pass 1.5: exclusive scan of the 196 bucket counts.
__global__ void k_bscan(const int* __restrict__ bcnt, int* __restrict__ bbase,
                        int* __restrict__ rowptr) {
    const int t = threadIdx.x;
    __shared__ int sc[256];
    const int v = (t < NB) ? bcnt[t] : 0;
    sc[t] = v;
    __syncthreads();
    for (int off = 1; off < 256; off <<= 1) {
        const int x = (t >= off) ? sc[t - off] : 0;
        __syncthreads();
        sc[t] += x;
        __syncthreads();
    }
    if (t < NB) bbase[t] = sc[t] - v;
    if (t == 0) rowptr[NN] = EE;
}

// Pass 2: one block per bucket — local hist+scan over 512 nodes,
// coalesced rowptr write, esrc scatter confined to this block's region.
__global__ __launch_bounds__(256)
void k_localcsr(const int* __restrict__ bcnt, const int* __restrict__ bbase,
                const int2* __restrict__ bbuf, int* __restrict__ rowptr,
                int* __restrict__ esrc) {
    const int b = blockIdx.x;
    const int t = threadIdx.x;
    const int cnt = bcnt[b];
    const int base = bbase[b];
    const int n0 = b * BSZ;
    const int nn = min(BSZ, NN - n0);
    __shared__ int lh[BSZ];
    __shared__ int lsc[BSZ];
    __shared__ int sc[256];
    for (int i = t; i < BSZ; i += 256) lh[i] = 0;
    __syncthreads();
    const int2* bb = bbuf + (size_t)b * CAP;
    for (int i = t; i < cnt; i += 256) atomicAdd(&lh[bb[i].y & (BSZ - 1)], 1);
    __syncthreads();
    const int a0 = lh[2 * t], a1 = lh[2 * t + 1];
    const int ts = a0 + a1;
    sc[t] = ts;
    __syncthreads();
    for (int off = 1; off < 256; off <<= 1) {
        const int x = (t >= off) ? sc[t - off] : 0;
        __syncthreads();
        sc[t] += x;
        __syncthreads();
    }
    const int ebase = sc[t] - ts;
    lsc[2 * t] = ebase;
    lsc[2 * t + 1] = ebase + a0;
    __syncthreads();
    for (int i = t; i < BSZ; i += 256) {
        if (i < nn) rowptr[n0 + i] = base + lsc[i];
        lh[i] = lsc[i];        // running counters
    }
    __syncthreads();
    for (int i = t; i < cnt; i += 256) {
        const int2 en = bb[i];
        const int p = atomicAdd(&lh[en.y & (BSZ - 1)], 1);
        esrc[base + p] = en.x;
    }
}

// ---------------- fused per-dst GAT layer: half-wave dual-edge layout ----------------
// Lane owns column pair (2l, 2l+1); half-wave h processes edge block [i+4h, i+4h+4).
// Per 8 edges: 8 broadcast esrc loads, 4 el gathers, 4 dword z-gathers, exp inline.
__global__ __launch_bounds__(256)
void k_gat_dst(const int* __restrict__ rowptr, const int* __restrict__ esrc,
               const float* __restrict__ el, const float* __restrict__ er,
               const unsigned* __restrict__ zb32, const float* __restrict__ hin,
               const float* __restrict__ bg, float* __restrict__ hout) {
    const int j  = threadIdx.x & 63;
    const int wv = threadIdx.x >> 6;
    const int d = blockIdx.x * 4 + wv;
    if (d >= NN) return;
    const int l    = j & 31;    // column pair index: cols 2l, 2l+1
    const int half = j >> 5;
    const int hh   = l >> 3;    // head of both columns
    const int r0 = rowptr[d], r1 = rowptr[d + 1];
    const float erh = er[d * NH + hh];
    float sum0 = 0.f, sum1 = 0.f, den = 0.f;
    for (int i = r0; i < r1; i += 8) {
        const int base = i + 4 * half;
        const int i0 = base, i1 = base + 1, i2 = base + 2, i3 = base + 3;
        const bool v0 = i0 < r1, v1 = i1 < r1, v2 = i2 < r1, v3 = i3 < r1;
        const unsigned s0 = (unsigned)esrc[v0 ? i0 : r0];
        const unsigned s1 = (unsigned)esrc[v1 ? i1 : r0];
        const unsigned s2 = (unsigned)esrc[v2 ? i2 : r0];
        const unsigned s3 = (unsigned)esrc[v3 ? i3 : r0];
        const float a0 = el[s0 * NH + hh];
        const float a1 = el[s1 * NH + hh];
        const float a2 = el[s2 * NH + hh];
        const float a3 = el[s3 * NH + hh];
        const unsigned zp0 = zb32[s0 * 32u + l];
        const unsigned zp1 = zb32[s1 * 32u + l];
        const unsigned zp2 = zb32[s2 * 32u + l];
        const unsigned zp3 = zb32[s3 * 32u + l];
        const float x0 = a0 + erh, x1 = a1 + erh, x2 = a2 + erh, x3 = a3 + erh;
        const float w0 = v0 ? __expf(fmaxf(x0, SLOPE * x0)) : 0.f;
        const float w1 = v1 ? __expf(fmaxf(x1, SLOPE * x1)) : 0.f;
        const float w2 = v2 ? __expf(fmaxf(x2, SLOPE * x2)) : 0.f;
        const float w3 = v3 ? __expf(fmaxf(x3, SLOPE * x3)) : 0.f;
        den  += (w0 + w1) + (w2 + w3);
        sum0 += (w0 * bflo(zp0) + w1 * bflo(zp1)) + (w2 * bflo(zp2) + w3 * bflo(zp3));
        sum1 += (w0 * bfhi(zp0) + w1 * bfhi(zp1)) + (w2 * bfhi(zp2) + w3 * bfhi(zp3));
    }
    // merge the two halves
    sum0 += __shfl_xor(sum0, 32, 64);
    sum1 += __shfl_xor(sum1, 32, 64);
    den  += __shfl_xor(den, 32, 64);
    if (half == 0) {
        const int c = 2 * l;
        const float2 hv = *(const float2*)(hin + (size_t)d * HID + c);
        const float2 bv = *(const float2*)(bg + c);
        float o0 = hv.x + bv.x;
        float o1 = hv.y + bv.y;
        if (r1 > r0) {
            const float rd = 1.f / den;
            o0 += sum0 * rd;
            o1 += sum1 * rd;
        }
        *(float2*)(hout + (size_t)d * HID + c) = make_float2(o0, o1);
    }
}

// LayerNorm + out = hn @ W_out + b_out. W column in registers.
__global__ __launch_bounds__(256, 4)
void k_ln_out(const float* __restrict__ h, const float* __restrict__ g,
              const float* __restrict__ be, const float* __restrict__ Wo,
              const float* __restrict__ bo, float* __restrict__ out) {
    const int j = threadIdx.x & 63;
    float Wreg[HID];
#pragma unroll
    for (int k = 0; k < HID; ++k) Wreg[k] = Wo[k * OUT_DIM + j];
    const float gj = g[j], bej = be[j], boj = bo[j];
    const int wid = (blockIdx.x * blockDim.x + threadIdx.x) >> 6;
    const int nw  = (gridDim.x * blockDim.x) >> 6;
    for (int v0 = wid * RB; v0 < NN; v0 += nw * RB) {
        float hn[RB];
#pragma unroll
        for (int r = 0; r < RB; ++r) {
            const float x = h[(size_t)(v0 + r) * HID + j];
            float s = x;
#pragma unroll
            for (int m = 32; m >= 1; m >>= 1) s += __shfl_xor(s, m, 64);
            const float mu = s * (1.f / 64.f);
            const float dx = x - mu;
            float vs = dx * dx;
#pragma unroll
            for (int m = 32; m >= 1; m >>= 1) vs += __shfl_xor(vs, m, 64);
            hn[r] = dx * rsqrtf(vs * (1.f / 64.f) + LN_EPS) * gj + bej;
        }
        float acc[RB];
#pragma unroll
        for (int r = 0; r < RB; ++r) acc[r] = boj;
#pragma unroll
        for (int k = 0; k < HID; ++k) {
#pragma unroll
            for (int r = 0; r < RB; ++r)
                acc[r] = fmaf(bcast(hn[r], k), Wreg[k], acc[r]);
        }
#pragma unroll
        for (int r = 0; r < RB; ++r) out[(size_t)(v0 + r) * OUT_DIM + j] = acc[r];
    }
}

extern "C" void kernel_launch(void* const* d_in, const int* in_sizes, int n_in,
                              void* d_out, int out_size, void* d_ws, size_t ws_size,
                              hipStream_t stream) {
    const float* X     = (const float*)d_in[0];
    const int*   src   = (const int*)d_in[1];
    const int*   dst   = (const int*)d_in[2];
    const float* W_in  = (const float*)d_in[3];
    const float* b_in  = (const float*)d_in[4];
    // d_in[5..8]: rewiring MLP params — output is dead, skipped entirely
    const float* W_gat = (const float*)d_in[9];   // (L,64,64)
    const float* a_l   = (const float*)d_in[10];  // (L,4,16)
    const float* a_r   = (const float*)d_in[11];
    const float* b_gat = (const float*)d_in[12];  // (L,64)
    const float* ln_g  = (const float*)d_in[13];
    const float* ln_b  = (const float*)d_in[14];
    const float* W_out = (const float*)d_in[15];
    const float* b_out = (const float*)d_in[16];
    float* out = (float*)d_out;

    float* ws = (float*)d_ws;
    float* hA = ws;                                   // N*64 f32
    float* hB = hA + (size_t)NN * HID;                // N*64 f32
    unsigned* zb32 = (unsigned*)(hB + (size_t)NN * HID);  // N*32 dwords (bf16 pairs)
    float* el = (float*)(zb32 + (size_t)NN * (HID / 2)); // N*4
    float* er = el + (size_t)NN * NH;                 // N*4
    int* rowptr = (int*)(er + (size_t)NN * NH);       // N+1 ints
    int* esrc   = rowptr + NN + 1;                    // E ints
    int* bcnt   = esrc + EE;                          // NB ints
    int* bbase  = bcnt + NB;                          // NB ints
    int2* bbuf  = (int2*)hB;  // 16.1 MB, aliases hB (dead until first k_gat_dst)

    k_in_gemm<<<1024, 256, 0, stream>>>(X, W_in, b_in, hA);

    // bucket-sort CSR by dst (built once, reused for all 3 layers)
    k_zero_bcnt<<<1, 256, 0, stream>>>(bcnt);
    k_bucketize<<<P1_BLOCKS, 256, 0, stream>>>(src, dst, bcnt, bbuf);
    k_bscan<<<1, 256, 0, stream>>>(bcnt, bbase, rowptr);
    k_localcsr<<<NB, 256, 0, stream>>>(bcnt, bbase, bbuf, rowptr, esrc);

    float* hin = hA;
    float* hout = hB;
    for (int l = 0; l < NL; ++l) {
        k_zgemm<<<1024, 256, 0, stream>>>(hin, W_gat + (size_t)l * HID * HID,
                                          a_l + (size_t)l * HID, a_r + (size_t)l * HID,
                                          zb32, el, er);
        k_gat_dst<<<(NN + 3) / 4, 256, 0, stream>>>(rowptr, esrc, el, er, zb32, hin,
                                                    b_gat + (size_t)l * HID, hout);
        float* t = hin; hin = hout; hout = t;
    }

    k_ln_out<<<1024, 256, 0, stream>>>(hin, ln_g, ln_b, W_out, b_out, out);
}

// Round 10
// 398.219 us; speedup vs baseline: 1.3854x; 1.1008x over previous
//
#include <hip/hip_runtime.h>

#define NN 100000
#define EE 1600000
#define IN_DIM 128
#define HID 64
#define NH 4
#define DH 16
#define NL 3
#define OUT_DIM 64
#define SLOPE 0.2f
#define LN_EPS 1e-5f
#define RB 4

// bucket CSR build
#define BSH 9
#define BSZ 512                               // nodes per bucket
#define NB ((NN + BSZ - 1) / BSZ)             // 196
#define CAP 10240                             // per-bucket capacity (avg 8163)
#define CHUNK 4096
#define P1_BLOCKS ((EE + CHUNK - 1) / CHUNK)  // 391

using short8 = __attribute__((ext_vector_type(8))) short;
using f32x4  = __attribute__((ext_vector_type(4))) float;

__device__ __forceinline__ float bcast(float x, int lane) {
    return __int_as_float(__builtin_amdgcn_readlane(__float_as_int(x), lane));
}
__device__ __forceinline__ unsigned f2bf(float x) {
    unsigned u = __float_as_uint(x);
    u += 0x7FFFu + ((u >> 16) & 1u);      // RNE
    return u >> 16;
}
__device__ __forceinline__ float bflo(unsigned zp) {   // low bf16 of dword
    return __uint_as_float(zp << 16);
}
__device__ __forceinline__ float bfhi(unsigned zp) {   // high bf16 of dword
    return __uint_as_float(zp & 0xFFFF0000u);
}

// ---------------- W_in pre-pack into MFMA B-fragment order ----------------
// Wb[(kk*4+nt)*64 + lane] = 8 bf16: B[k = kk*32 + (lane>>4)*8 + e][n = nt*16 + (lane&15)]
__global__ void k_wpack(const float* __restrict__ W, uint4* __restrict__ Wb) {
    const int tid = blockIdx.x * 256 + threadIdx.x;
    if (tid >= 1024) return;
    const int lane = tid & 63;
    const int ntkk = tid >> 6;              // 0..15
    const int nt = ntkk & 3, kk = ntkk >> 2;
    const int k0 = kk * 32 + (lane >> 4) * 8;
    const int n  = nt * 16 + (lane & 15);
    unsigned dw[4];
#pragma unroll
    for (int p = 0; p < 4; ++p) {
        const unsigned lo = f2bf(W[(k0 + 2 * p) * HID + n]);
        const unsigned hi = f2bf(W[(k0 + 2 * p + 1) * HID + n]);
        dw[p] = lo | (hi << 16);
    }
    Wb[ntkk * 64 + lane] = make_uint4(dw[0], dw[1], dw[2], dw[3]);
}

// h0 = X @ W_in + b_in via MFMA. One wave = 16 rows x 64 cols, K=128 in 4 steps.
__global__ __launch_bounds__(256)
void k_in_gemm(const float* __restrict__ X, const uint4* __restrict__ Wb,
               const float* __restrict__ b, float* __restrict__ h) {
    const int l  = threadIdx.x & 63;
    const int wv = threadIdx.x >> 6;
    const int wrow = blockIdx.x * 64 + wv * 16;
    if (wrow >= NN) return;
    const int arow = wrow + (l & 15);
    const int kb_off = (l >> 4) * 8;
    f32x4 acc[4];
#pragma unroll
    for (int nt = 0; nt < 4; ++nt) acc[nt] = (f32x4){0.f, 0.f, 0.f, 0.f};
    const float* xr = X + (size_t)arow * IN_DIM;
#pragma unroll
    for (int kk = 0; kk < 4; ++kk) {
        const int kb = kk * 32 + kb_off;
        const float4 xa = *(const float4*)(xr + kb);
        const float4 xb = *(const float4*)(xr + kb + 4);
        const unsigned d0 = f2bf(xa.x) | (f2bf(xa.y) << 16);
        const unsigned d1 = f2bf(xa.z) | (f2bf(xa.w) << 16);
        const unsigned d2 = f2bf(xb.x) | (f2bf(xb.y) << 16);
        const unsigned d3 = f2bf(xb.z) | (f2bf(xb.w) << 16);
        const uint4 au = make_uint4(d0, d1, d2, d3);
        const short8 af = __builtin_bit_cast(short8, au);
#pragma unroll
        for (int nt = 0; nt < 4; ++nt) {
            const uint4 bu = Wb[(kk * 4 + nt) * 64 + l];
            const short8 bf = __builtin_bit_cast(short8, bu);
            acc[nt] = __builtin_amdgcn_mfma_f32_16x16x32_bf16(af, bf, acc[nt], 0, 0, 0);
        }
    }
    const int grp = l >> 4, ci = l & 15;
#pragma unroll
    for (int nt = 0; nt < 4; ++nt) {
        const int col = nt * 16 + ci;
        const float bv = b[col];
#pragma unroll
        for (int r = 0; r < 4; ++r) {
            h[(size_t)(wrow + grp * 4 + r) * HID + col] = acc[nt][r] + bv;
        }
    }
}

// z(bf16) = h @ W (64x64) + el/er head reductions. W column in registers.
__global__ __launch_bounds__(256, 4)
void k_zgemm(const float* __restrict__ h, const float* __restrict__ W,
             const float* __restrict__ al, const float* __restrict__ ar,
             unsigned* __restrict__ zb32,
             float* __restrict__ el, float* __restrict__ er) {
    const int j = threadIdx.x & 63;
    float Wreg[HID];
#pragma unroll
    for (int k = 0; k < HID; ++k) Wreg[k] = W[k * HID + j];
    const float alj = al[j];
    const float arj = ar[j];
    const int head = j >> 4;
    const int wid = (blockIdx.x * blockDim.x + threadIdx.x) >> 6;
    const int nw  = (gridDim.x * blockDim.x) >> 6;
    for (int v0 = wid * RB; v0 < NN; v0 += nw * RB) {
        float hv[RB];
#pragma unroll
        for (int r = 0; r < RB; ++r) hv[r] = h[(size_t)(v0 + r) * HID + j];
        float acc[RB];
#pragma unroll
        for (int r = 0; r < RB; ++r) acc[r] = 0.f;
#pragma unroll
        for (int k = 0; k < HID; ++k) {
#pragma unroll
            for (int r = 0; r < RB; ++r)
                acc[r] = fmaf(bcast(hv[r], k), Wreg[k], acc[r]);
        }
#pragma unroll
        for (int r = 0; r < RB; ++r) {
            const unsigned my = f2bf(acc[r]);
            const unsigned ot = (unsigned)__shfl_xor((int)my, 1, 64);
            if ((j & 1) == 0)
                zb32[(size_t)(v0 + r) * (HID / 2) + (j >> 1)] = my | (ot << 16);
            float pl = acc[r] * alj, pr = acc[r] * arj;
#pragma unroll
            for (int m = 8; m >= 1; m >>= 1) {
                pl += __shfl_xor(pl, m, 64);
                pr += __shfl_xor(pr, m, 64);
            }
            if ((j & 15) == 0) {
                el[(v0 + r) * NH + head] = pl;
                er[(v0 + r) * NH + head] = pr;
            }
        }
    }
}

// ---------------- bucket-sort CSR build ----------------

__global__ void k_zero_bcnt(int* __restrict__ bcnt) {
    if (threadIdx.x < NB) bcnt[threadIdx.x] = 0;
}

// Pass 1: block-local counting sort by bucket (d>>9), contiguous copy-out.
__global__ __launch_bounds__(256)
void k_bucketize(const int* __restrict__ src, const int* __restrict__ dst,
                 int* __restrict__ bcnt, int2* __restrict__ bbuf) {
    __shared__ int lh[256];      // hist -> running counter
    __shared__ int lbase[256];   // exclusive prefix
    __shared__ int lcnt[256];    // saved counts
    __shared__ int gbase[256];
    __shared__ int sc[256];
    __shared__ int2 stage[CHUNK];  // 32 KB
    const int t = threadIdx.x;
    const int e0 = blockIdx.x * CHUNK;
    const int n = min(CHUNK, EE - e0);
    lh[t] = 0;
    __syncthreads();
    int myd[CHUNK / 256], mys[CHUNK / 256];
#pragma unroll
    for (int i = 0; i < CHUNK / 256; ++i) {
        const int o = i * 256 + t;
        if (o < n) {
            myd[i] = dst[e0 + o];
            mys[i] = src[e0 + o];
            atomicAdd(&lh[myd[i] >> BSH], 1);
        } else myd[i] = -1;
    }
    __syncthreads();
    {   // exclusive scan of lh
        const int v = lh[t];
        lcnt[t] = v;
        sc[t] = v;
        __syncthreads();
        for (int off = 1; off < 256; off <<= 1) {
            const int x = (t >= off) ? sc[t - off] : 0;
            __syncthreads();
            sc[t] += x;
            __syncthreads();
        }
        lbase[t] = sc[t] - v;
        lh[t] = sc[t] - v;     // running counter
    }
    __syncthreads();
#pragma unroll
    for (int i = 0; i < CHUNK / 256; ++i) {
        if (myd[i] >= 0) {
            const int b = myd[i] >> BSH;
            const int p = atomicAdd(&lh[b], 1);
            stage[p] = make_int2(mys[i], myd[i]);
        }
    }
    __syncthreads();
    if (t < NB && lcnt[t] > 0) gbase[t] = atomicAdd(&bcnt[t], lcnt[t]);
    __syncthreads();
    for (int i = t; i < n; i += 256) {
        const int2 en = stage[i];
        const int b = en.y >> BSH;
        const int gp = gbase[b] + (i - lbase[b]);
        if (gp < CAP) bbuf[(size_t)b * CAP + gp] = en;
    }
}

// Pass 1.5: exclusive scan of the 196 bucket counts.
__global__ void k_bscan(const int* __restrict__ bcnt, int* __restrict__ bbase,
                        int* __restrict__ rowptr) {
    const int t = threadIdx.x;
    __shared__ int sc[256];
    const int v = (t < NB) ? bcnt[t] : 0;
    sc[t] = v;
    __syncthreads();
    for (int off = 1; off < 256; off <<= 1) {
        const int x = (t >= off) ? sc[t - off] : 0;
        __syncthreads();
        sc[t] += x;
        __syncthreads();
    }
    if (t < NB) bbase[t] = sc[t] - v;
    if (t == 0) rowptr[NN] = EE;
}

// Pass 2: one block per bucket — local hist+scan over 512 nodes,
// coalesced rowptr write, esrc scatter confined to this block's region.
__global__ __launch_bounds__(256)
void k_localcsr(const int* __restrict__ bcnt, const int* __restrict__ bbase,
                const int2* __restrict__ bbuf, int* __restrict__ rowptr,
                int* __restrict__ esrc) {
    const int b = blockIdx.x;
    const int t = threadIdx.x;
    const int cnt = bcnt[b];
    const int base = bbase[b];
    const int n0 = b * BSZ;
    const int nn = min(BSZ, NN - n0);
    __shared__ int lh[BSZ];
    __shared__ int lsc[BSZ];
    __shared__ int sc[256];
    for (int i = t; i < BSZ; i += 256) lh[i] = 0;
    __syncthreads();
    const int2* bb = bbuf + (size_t)b * CAP;
    for (int i = t; i < cnt; i += 256) atomicAdd(&lh[bb[i].y & (BSZ - 1)], 1);
    __syncthreads();
    const int a0 = lh[2 * t], a1 = lh[2 * t + 1];
    const int ts = a0 + a1;
    sc[t] = ts;
    __syncthreads();
    for (int off = 1; off < 256; off <<= 1) {
        const int x = (t >= off) ? sc[t - off] : 0;
        __syncthreads();
        sc[t] += x;
        __syncthreads();
    }
    const int ebase = sc[t] - ts;
    lsc[2 * t] = ebase;
    lsc[2 * t + 1] = ebase + a0;
    __syncthreads();
    for (int i = t; i < BSZ; i += 256) {
        if (i < nn) rowptr[n0 + i] = base + lsc[i];
        lh[i] = lsc[i];        // running counters
    }
    __syncthreads();
    for (int i = t; i < cnt; i += 256) {
        const int2 en = bb[i];
        const int p = atomicAdd(&lh[en.y & (BSZ - 1)], 1);
        esrc[base + p] = en.x;
    }
}

// ---------------- fused per-dst GAT layer: half-wave, 16-edge pipeline ----------------
__global__ __launch_bounds__(256)
void k_gat_dst(const int* __restrict__ rowptr, const int* __restrict__ esrc,
               const float* __restrict__ el, const float* __restrict__ er,
               const unsigned* __restrict__ zb32, const float* __restrict__ hin,
               const float* __restrict__ bg, float* __restrict__ hout) {
    const int j  = threadIdx.x & 63;
    const int wv = threadIdx.x >> 6;
    const int d = blockIdx.x * 4 + wv;
    if (d >= NN) return;
    const int l    = j & 31;    // column pair index: cols 2l, 2l+1
    const int half = j >> 5;
    const int hh   = l >> 3;    // head of both columns
    const int r0 = rowptr[d], r1 = rowptr[d + 1];
    const float erh = er[d * NH + hh];
    float sum0 = 0.f, sum1 = 0.f, den = 0.f;
    for (int i = r0; i < r1; i += 16) {
        int ii[8]; bool vv[8]; unsigned s[8];
#pragma unroll
        for (int u = 0; u < 8; ++u) {
            ii[u] = i + ((u & 4) << 1) + 4 * half + (u & 3);
            vv[u] = ii[u] < r1;
            s[u] = (unsigned)esrc[vv[u] ? ii[u] : r0];
        }
        float a[8];
#pragma unroll
        for (int u = 0; u < 8; ++u) a[u] = el[s[u] * NH + hh];
        unsigned zp[8];
#pragma unroll
        for (int u = 0; u < 8; ++u) zp[u] = zb32[s[u] * 32u + l];
#pragma unroll
        for (int u = 0; u < 8; ++u) {
            const float x = a[u] + erh;
            const float w = vv[u] ? __expf(fmaxf(x, SLOPE * x)) : 0.f;
            den  += w;
            sum0 += w * bflo(zp[u]);
            sum1 += w * bfhi(zp[u]);
        }
    }
    // merge the two halves
    sum0 += __shfl_xor(sum0, 32, 64);
    sum1 += __shfl_xor(sum1, 32, 64);
    den  += __shfl_xor(den, 32, 64);
    if (half == 0) {
        const int c = 2 * l;
        const float2 hv = *(const float2*)(hin + (size_t)d * HID + c);
        const float2 bv = *(const float2*)(bg + c);
        float o0 = hv.x + bv.x;
        float o1 = hv.y + bv.y;
        if (r1 > r0) {
            const float rd = 1.f / den;
            o0 += sum0 * rd;
            o1 += sum1 * rd;
        }
        *(float2*)(hout + (size_t)d * HID + c) = make_float2(o0, o1);
    }
}

// LayerNorm + out = hn @ W_out + b_out. W column in registers.
__global__ __launch_bounds__(256, 4)
void k_ln_out(const float* __restrict__ h, const float* __restrict__ g,
              const float* __restrict__ be, const float* __restrict__ Wo,
              const float* __restrict__ bo, float* __restrict__ out) {
    const int j = threadIdx.x & 63;
    float Wreg[HID];
#pragma unroll
    for (int k = 0; k < HID; ++k) Wreg[k] = Wo[k * OUT_DIM + j];
    const float gj = g[j], bej = be[j], boj = bo[j];
    const int wid = (blockIdx.x * blockDim.x + threadIdx.x) >> 6;
    const int nw  = (gridDim.x * blockDim.x) >> 6;
    for (int v0 = wid * RB; v0 < NN; v0 += nw * RB) {
        float hn[RB];
#pragma unroll
        for (int r = 0; r < RB; ++r) {
            const float x = h[(size_t)(v0 + r) * HID + j];
            float s = x;
#pragma unroll
            for (int m = 32; m >= 1; m >>= 1) s += __shfl_xor(s, m, 64);
            const float mu = s * (1.f / 64.f);
            const float dx = x - mu;
            float vs = dx * dx;
#pragma unroll
            for (int m = 32; m >= 1; m >>= 1) vs += __shfl_xor(vs, m, 64);
            hn[r] = dx * rsqrtf(vs * (1.f / 64.f) + LN_EPS) * gj + bej;
        }
        float acc[RB];
#pragma unroll
        for (int r = 0; r < RB; ++r) acc[r] = boj;
#pragma unroll
        for (int k = 0; k < HID; ++k) {
#pragma unroll
            for (int r = 0; r < RB; ++r)
                acc[r] = fmaf(bcast(hn[r], k), Wreg[k], acc[r]);
        }
#pragma unroll
        for (int r = 0; r < RB; ++r) out[(size_t)(v0 + r) * OUT_DIM + j] = acc[r];
    }
}

extern "C" void kernel_launch(void* const* d_in, const int* in_sizes, int n_in,
                              void* d_out, int out_size, void* d_ws, size_t ws_size,
                              hipStream_t stream) {
    const float* X     = (const float*)d_in[0];
    const int*   src   = (const int*)d_in[1];
    const int*   dst   = (const int*)d_in[2];
    const float* W_in  = (const float*)d_in[3];
    const float* b_in  = (const float*)d_in[4];
    // d_in[5..8]: rewiring MLP params — output is dead, skipped entirely
    const float* W_gat = (const float*)d_in[9];   // (L,64,64)
    const float* a_l   = (const float*)d_in[10];  // (L,4,16)
    const float* a_r   = (const float*)d_in[11];
    const float* b_gat = (const float*)d_in[12];  // (L,64)
    const float* ln_g  = (const float*)d_in[13];
    const float* ln_b  = (const float*)d_in[14];
    const float* W_out = (const float*)d_in[15];
    const float* b_out = (const float*)d_in[16];
    float* out = (float*)d_out;

    float* ws = (float*)d_ws;
    float* hA = ws;                                   // N*64 f32
    float* hB = hA + (size_t)NN * HID;                // N*64 f32
    unsigned* zb32 = (unsigned*)(hB + (size_t)NN * HID);  // N*32 dwords (bf16 pairs)
    float* el = (float*)(zb32 + (size_t)NN * (HID / 2)); // N*4
    float* er = el + (size_t)NN * NH;                 // N*4
    int* rowptr = (int*)(er + (size_t)NN * NH);       // N+1 ints
    int* esrc   = rowptr + NN + 1;                    // E ints
    int* bcnt   = esrc + EE;                          // NB ints
    int* bbase  = bcnt + NB;                          // NB ints
    uintptr_t wp = (uintptr_t)(bbase + NB);
    wp = (wp + 15) & ~(uintptr_t)15;
    uint4* Wb   = (uint4*)wp;                         // 16 KB MFMA-packed W_in
    int2* bbuf  = (int2*)hB;  // 16.1 MB, aliases hB (dead until first k_gat_dst)

    k_wpack<<<4, 256, 0, stream>>>(W_in, Wb);
    k_in_gemm<<<(NN + 63) / 64, 256, 0, stream>>>(X, Wb, b_in, hA);

    // bucket-sort CSR by dst (built once, reused for all 3 layers)
    k_zero_bcnt<<<1, 256, 0, stream>>>(bcnt);
    k_bucketize<<<P1_BLOCKS, 256, 0, stream>>>(src, dst, bcnt, bbuf);
    k_bscan<<<1, 256, 0, stream>>>(bcnt, bbase, rowptr);
    k_localcsr<<<NB, 256, 0, stream>>>(bcnt, bbase, bbuf, rowptr, esrc);

    float* hin = hA;
    float* hout = hB;
    for (int l = 0; l < NL; ++l) {
        k_zgemm<<<1024, 256, 0, stream>>>(hin, W_gat + (size_t)l * HID * HID,
                                          a_l + (size_t)l * HID, a_r + (size_t)l * HID,
                                          zb32, el, er);
        k_gat_dst<<<(NN + 3) / 4, 256, 0, stream>>>(rowptr, esrc, el, er, zb32, hin,
                                                    b_gat + (size_t)l * HID, hout);
        float* t = hin; hin = hout; hout = t;
    }

    k_ln_out<<<1024, 256, 0, stream>>>(hin, ln_g, ln_b, W_out, b_out, out);
}

// Round 11
// 300.137 us; speedup vs baseline: 1.8381x; 1.3268x over previous
//
#include <hip/hip_runtime.h>

#define NN 100000
#define EE 1600000
#define IN_DIM 128
#define HID 64
#define NH 4
#define DH 16
#define NL 3
#define OUT_DIM 64
#define SLOPE 0.2f
#define LN_EPS 1e-5f
#define RB 4

// bucket CSR build
#define BSH 9
#define BSZ 512                               // nodes per bucket
#define NB ((NN + BSZ - 1) / BSZ)             // 196
#define CAP 10240                             // per-bucket capacity (avg 8163)
#define CHUNK 4096
#define P1_BLOCKS ((EE + CHUNK - 1) / CHUNK)  // 391

using short8 = __attribute__((ext_vector_type(8))) short;
using f32x4  = __attribute__((ext_vector_type(4))) float;

__device__ __forceinline__ float bcast(float x, int lane) {
    return __int_as_float(__builtin_amdgcn_readlane(__float_as_int(x), lane));
}
__device__ __forceinline__ unsigned f2bf(float x) {
    unsigned u = __float_as_uint(x);
    u += 0x7FFFu + ((u >> 16) & 1u);      // RNE
    return u >> 16;
}
__device__ __forceinline__ float bflo(unsigned zp) {   // low bf16 of dword
    return __uint_as_float(zp << 16);
}
__device__ __forceinline__ float bfhi(unsigned zp) {   // high bf16 of dword
    return __uint_as_float(zp & 0xFFFF0000u);
}

// ---------------- W_in pre-pack into MFMA B-fragment order ----------------
// Wb[(kk*4+nt)*64 + lane] = 8 bf16: B[k = kk*32 + (lane>>4)*8 + e][n = nt*16 + (lane&15)]
__global__ void k_wpack(const float* __restrict__ W, uint4* __restrict__ Wb) {
    const int tid = blockIdx.x * 256 + threadIdx.x;
    if (tid >= 1024) return;
    const int lane = tid & 63;
    const int ntkk = tid >> 6;              // 0..15
    const int nt = ntkk & 3, kk = ntkk >> 2;
    const int k0 = kk * 32 + (lane >> 4) * 8;
    const int n  = nt * 16 + (lane & 15);
    unsigned dw[4];
#pragma unroll
    for (int p = 0; p < 4; ++p) {
        const unsigned lo = f2bf(W[(k0 + 2 * p) * HID + n]);
        const unsigned hi = f2bf(W[(k0 + 2 * p + 1) * HID + n]);
        dw[p] = lo | (hi << 16);
    }
    Wb[ntkk * 64 + lane] = make_uint4(dw[0], dw[1], dw[2], dw[3]);
}

// ---------------- per-layer GAT W pre-pack (5 N-tiles: z cols + fused el/er) ----
// nt 0..3: B[k][n] = W[k][nt*16+n]   (the z GEMM)
// nt 4   : B[k][c] = sum_d W[k][c*16+d]*al[c*16+d]        (c<4: el heads)
//                    sum_d W[k][(c-4)*16+d]*ar[(c-4)*16+d] (4<=c<8: er heads)
//                    0                                     (c>=8)
__device__ float walv(const float* __restrict__ W, const float* __restrict__ al,
                      const float* __restrict__ ar, int k, int c) {
    if (c < 4) {
        float s = 0.f;
#pragma unroll
        for (int d = 0; d < 16; ++d) s += W[k * HID + c * 16 + d] * al[c * 16 + d];
        return s;
    }
    if (c < 8) {
        const int hh = c - 4;
        float s = 0.f;
#pragma unroll
        for (int d = 0; d < 16; ++d) s += W[k * HID + hh * 16 + d] * ar[hh * 16 + d];
        return s;
    }
    return 0.f;
}

__global__ void k_wpack_gat(const float* __restrict__ W_gat, const float* __restrict__ a_l,
                            const float* __restrict__ a_r, uint4* __restrict__ Wbg) {
    const int l = blockIdx.y;
    const int tid = blockIdx.x * 256 + threadIdx.x;
    if (tid >= 640) return;
    const int lane = tid & 63;
    const int f = tid >> 6;                 // 0..9
    const int kk = f / 5, nt = f % 5;
    const float* W  = W_gat + (size_t)l * HID * HID;
    const float* al = a_l + (size_t)l * HID;
    const float* ar = a_r + (size_t)l * HID;
    const int k0 = kk * 32 + (lane >> 4) * 8;
    const int n  = lane & 15;
    unsigned dw[4];
#pragma unroll
    for (int p = 0; p < 4; ++p) {
        float b0, b1;
        if (nt < 4) {
            b0 = W[(k0 + 2 * p) * HID + nt * 16 + n];
            b1 = W[(k0 + 2 * p + 1) * HID + nt * 16 + n];
        } else {
            b0 = walv(W, al, ar, k0 + 2 * p, n);
            b1 = walv(W, al, ar, k0 + 2 * p + 1, n);
        }
        dw[p] = f2bf(b0) | (f2bf(b1) << 16);
    }
    Wbg[(size_t)l * 640 + f * 64 + lane] = make_uint4(dw[0], dw[1], dw[2], dw[3]);
}

// h0 = X @ W_in + b_in via MFMA. One wave = 16 rows x 64 cols, K=128 in 4 steps.
__global__ __launch_bounds__(256)
void k_in_gemm(const float* __restrict__ X, const uint4* __restrict__ Wb,
               const float* __restrict__ b, float* __restrict__ h) {
    const int l  = threadIdx.x & 63;
    const int wv = threadIdx.x >> 6;
    const int wrow = blockIdx.x * 64 + wv * 16;
    if (wrow >= NN) return;
    const int arow = wrow + (l & 15);
    const int kb_off = (l >> 4) * 8;
    f32x4 acc[4];
#pragma unroll
    for (int nt = 0; nt < 4; ++nt) acc[nt] = (f32x4){0.f, 0.f, 0.f, 0.f};
    const float* xr = X + (size_t)arow * IN_DIM;
#pragma unroll
    for (int kk = 0; kk < 4; ++kk) {
        const int kb = kk * 32 + kb_off;
        const float4 xa = *(const float4*)(xr + kb);
        const float4 xb = *(const float4*)(xr + kb + 4);
        const unsigned d0 = f2bf(xa.x) | (f2bf(xa.y) << 16);
        const unsigned d1 = f2bf(xa.z) | (f2bf(xa.w) << 16);
        const unsigned d2 = f2bf(xb.x) | (f2bf(xb.y) << 16);
        const unsigned d3 = f2bf(xb.z) | (f2bf(xb.w) << 16);
        const uint4 au = make_uint4(d0, d1, d2, d3);
        const short8 af = __builtin_bit_cast(short8, au);
#pragma unroll
        for (int nt = 0; nt < 4; ++nt) {
            const uint4 bu = Wb[(kk * 4 + nt) * 64 + l];
            const short8 bf = __builtin_bit_cast(short8, bu);
            acc[nt] = __builtin_amdgcn_mfma_f32_16x16x32_bf16(af, bf, acc[nt], 0, 0, 0);
        }
    }
    const int grp = l >> 4, ci = l & 15;
#pragma unroll
    for (int nt = 0; nt < 4; ++nt) {
        const int col = nt * 16 + ci;
        const float bv = b[col];
#pragma unroll
        for (int r = 0; r < 4; ++r) {
            h[(size_t)(wrow + grp * 4 + r) * HID + col] = acc[nt][r] + bv;
        }
    }
}

// z(bf16) = h @ W + fused el/er via 5th MFMA N-tile. One wave = 16 rows.
__global__ __launch_bounds__(256)
void k_zgemm(const float* __restrict__ h, const uint4* __restrict__ Wbg,
             unsigned* __restrict__ zb32, float* __restrict__ el, float* __restrict__ er) {
    const int l  = threadIdx.x & 63;
    const int wv = threadIdx.x >> 6;
    const int wrow = blockIdx.x * 64 + wv * 16;
    if (wrow >= NN) return;
    const int arow = wrow + (l & 15);
    const int kb_off = (l >> 4) * 8;
    f32x4 acc[5];
#pragma unroll
    for (int nt = 0; nt < 5; ++nt) acc[nt] = (f32x4){0.f, 0.f, 0.f, 0.f};
    const float* hr = h + (size_t)arow * HID;
#pragma unroll
    for (int kk = 0; kk < 2; ++kk) {
        const int kb = kk * 32 + kb_off;
        const float4 xa = *(const float4*)(hr + kb);
        const float4 xb = *(const float4*)(hr + kb + 4);
        const unsigned d0 = f2bf(xa.x) | (f2bf(xa.y) << 16);
        const unsigned d1 = f2bf(xa.z) | (f2bf(xa.w) << 16);
        const unsigned d2 = f2bf(xb.x) | (f2bf(xb.y) << 16);
        const unsigned d3 = f2bf(xb.z) | (f2bf(xb.w) << 16);
        const uint4 au = make_uint4(d0, d1, d2, d3);
        const short8 af = __builtin_bit_cast(short8, au);
#pragma unroll
        for (int nt = 0; nt < 5; ++nt) {
            const uint4 bu = Wbg[(kk * 5 + nt) * 64 + l];
            const short8 bf = __builtin_bit_cast(short8, bu);
            acc[nt] = __builtin_amdgcn_mfma_f32_16x16x32_bf16(af, bf, acc[nt], 0, 0, 0);
        }
    }
    const int grp = l >> 4, ci = l & 15;
    // z: pack bf16 col-pairs, even-ci lanes store dwords
#pragma unroll
    for (int nt = 0; nt < 4; ++nt) {
#pragma unroll
        for (int r = 0; r < 4; ++r) {
            const int row = wrow + grp * 4 + r;
            const unsigned my = f2bf(acc[nt][r]);
            const unsigned ot = (unsigned)__shfl_xor((int)my, 1, 64);
            if ((ci & 1) == 0)
                zb32[(size_t)row * 32 + nt * 8 + (ci >> 1)] = my | (ot << 16);
        }
    }
    // el/er direct from 5th tile
#pragma unroll
    for (int r = 0; r < 4; ++r) {
        const int row = wrow + grp * 4 + r;
        const float v = acc[4][r];
        if (ci < 4) el[row * NH + ci] = v;
        else if (ci < 8) er[row * NH + (ci - 4)] = v;
    }
}

// ---------------- bucket-sort CSR build ----------------

__global__ void k_zero_bcnt(int* __restrict__ bcnt) {
    if (threadIdx.x < NB) bcnt[threadIdx.x] = 0;
}

// Pass 1: block-local counting sort by bucket (d>>9), contiguous copy-out.
__global__ __launch_bounds__(256)
void k_bucketize(const int* __restrict__ src, const int* __restrict__ dst,
                 int* __restrict__ bcnt, int2* __restrict__ bbuf) {
    __shared__ int lh[256];      // hist -> running counter
    __shared__ int lbase[256];   // exclusive prefix
    __shared__ int lcnt[256];    // saved counts
    __shared__ int gbase[256];
    __shared__ int sc[256];
    __shared__ int2 stage[CHUNK];  // 32 KB
    const int t = threadIdx.x;
    const int e0 = blockIdx.x * CHUNK;
    const int n = min(CHUNK, EE - e0);
    lh[t] = 0;
    __syncthreads();
    int myd[CHUNK / 256], mys[CHUNK / 256];
#pragma unroll
    for (int i = 0; i < CHUNK / 256; ++i) {
        const int o = i * 256 + t;
        if (o < n) {
            myd[i] = dst[e0 + o];
            mys[i] = src[e0 + o];
            atomicAdd(&lh[myd[i] >> BSH], 1);
        } else myd[i] = -1;
    }
    __syncthreads();
    {   // exclusive scan of lh
        const int v = lh[t];
        lcnt[t] = v;
        sc[t] = v;
        __syncthreads();
        for (int off = 1; off < 256; off <<= 1) {
            const int x = (t >= off) ? sc[t - off] : 0;
            __syncthreads();
            sc[t] += x;
            __syncthreads();
        }
        lbase[t] = sc[t] - v;
        lh[t] = sc[t] - v;     // running counter
    }
    __syncthreads();
#pragma unroll
    for (int i = 0; i < CHUNK / 256; ++i) {
        if (myd[i] >= 0) {
            const int b = myd[i] >> BSH;
            const int p = atomicAdd(&lh[b], 1);
            stage[p] = make_int2(mys[i], myd[i]);
        }
    }
    __syncthreads();
    if (t < NB && lcnt[t] > 0) gbase[t] = atomicAdd(&bcnt[t], lcnt[t]);
    __syncthreads();
    for (int i = t; i < n; i += 256) {
        const int2 en = stage[i];
        const int b = en.y >> BSH;
        const int gp = gbase[b] + (i - lbase[b]);
        if (gp < CAP) bbuf[(size_t)b * CAP + gp] = en;
    }
}

// Pass 1.5: exclusive scan of the 196 bucket counts.
__global__ void k_bscan(const int* __restrict__ bcnt, int* __restrict__ bbase,
                        int* __restrict__ rowptr) {
    const int t = threadIdx.x;
    __shared__ int sc[256];
    const int v = (t < NB) ? bcnt[t] : 0;
    sc[t] = v;
    __syncthreads();
    for (int off = 1; off < 256; off <<= 1) {
        const int x = (t >= off) ? sc[t - off] : 0;
        __syncthreads();
        sc[t] += x;
        __syncthreads();
    }
    if (t < NB) bbase[t] = sc[t] - v;
    if (t == 0) rowptr[NN] = EE;
}

// Pass 2: one block per bucket — local hist+scan over 512 nodes,
// coalesced rowptr write, esrc scatter confined to this block's region.
__global__ __launch_bounds__(256)
void k_localcsr(const int* __restrict__ bcnt, const int* __restrict__ bbase,
                const int2* __restrict__ bbuf, int* __restrict__ rowptr,
                int* __restrict__ esrc) {
    const int b = blockIdx.x;
    const int t = threadIdx.x;
    const int cnt = bcnt[b];
    const int base = bbase[b];
    const int n0 = b * BSZ;
    const int nn = min(BSZ, NN - n0);
    __shared__ int lh[BSZ];
    __shared__ int lsc[BSZ];
    __shared__ int sc[256];
    for (int i = t; i < BSZ; i += 256) lh[i] = 0;
    __syncthreads();
    const int2* bb = bbuf + (size_t)b * CAP;
    for (int i = t; i < cnt; i += 256) atomicAdd(&lh[bb[i].y & (BSZ - 1)], 1);
    __syncthreads();
    const int a0 = lh[2 * t], a1 = lh[2 * t + 1];
    const int ts = a0 + a1;
    sc[t] = ts;
    __syncthreads();
    for (int off = 1; off < 256; off <<= 1) {
        const int x = (t >= off) ? sc[t - off] : 0;
        __syncthreads();
        sc[t] += x;
        __syncthreads();
    }
    const int ebase = sc[t] - ts;
    lsc[2 * t] = ebase;
    lsc[2 * t + 1] = ebase + a0;
    __syncthreads();
    for (int i = t; i < BSZ; i += 256) {
        if (i < nn) rowptr[n0 + i] = base + lsc[i];
        lh[i] = lsc[i];        // running counters
    }
    __syncthreads();
    for (int i = t; i < cnt; i += 256) {
        const int2 en = bb[i];
        const int p = atomicAdd(&lh[en.y & (BSZ - 1)], 1);
        esrc[base + p] = en.x;
    }
}

// ---------------- fused per-dst GAT layer: half-wave, 16-edge pipeline ----------------
__global__ __launch_bounds__(256)
void k_gat_dst(const int* __restrict__ rowptr, const int* __restrict__ esrc,
               const float* __restrict__ el, const float* __restrict__ er,
               const unsigned* __restrict__ zb32, const float* __restrict__ hin,
               const float* __restrict__ bg, float* __restrict__ hout) {
    const int j  = threadIdx.x & 63;
    const int wv = threadIdx.x >> 6;
    const int d = blockIdx.x * 4 + wv;
    if (d >= NN) return;
    const int l    = j & 31;    // column pair index: cols 2l, 2l+1
    const int half = j >> 5;
    const int hh   = l >> 3;    // head of both columns
    const int r0 = rowptr[d], r1 = rowptr[d + 1];
    const float erh = er[d * NH + hh];
    float sum0 = 0.f, sum1 = 0.f, den = 0.f;
    for (int i = r0; i < r1; i += 16) {
        int ii[8]; bool vv[8]; unsigned s[8];
#pragma unroll
        for (int u = 0; u < 8; ++u) {
            ii[u] = i + ((u & 4) << 1) + 4 * half + (u & 3);
            vv[u] = ii[u] < r1;
            s[u] = (unsigned)esrc[vv[u] ? ii[u] : r0];
        }
        float a[8];
#pragma unroll
        for (int u = 0; u < 8; ++u) a[u] = el[s[u] * NH + hh];
        unsigned zp[8];
#pragma unroll
        for (int u = 0; u < 8; ++u) zp[u] = zb32[s[u] * 32u + l];
#pragma unroll
        for (int u = 0; u < 8; ++u) {
            const float x = a[u] + erh;
            const float w = vv[u] ? __expf(fmaxf(x, SLOPE * x)) : 0.f;
            den  += w;
            sum0 += w * bflo(zp[u]);
            sum1 += w * bfhi(zp[u]);
        }
    }
    // merge the two halves
    sum0 += __shfl_xor(sum0, 32, 64);
    sum1 += __shfl_xor(sum1, 32, 64);
    den  += __shfl_xor(den, 32, 64);
    if (half == 0) {
        const int c = 2 * l;
        const float2 hv = *(const float2*)(hin + (size_t)d * HID + c);
        const float2 bv = *(const float2*)(bg + c);
        float o0 = hv.x + bv.x;
        float o1 = hv.y + bv.y;
        if (r1 > r0) {
            const float rd = 1.f / den;
            o0 += sum0 * rd;
            o1 += sum1 * rd;
        }
        *(float2*)(hout + (size_t)d * HID + c) = make_float2(o0, o1);
    }
}

// LayerNorm + out = hn @ W_out + b_out. W column in registers.
__global__ __launch_bounds__(256, 4)
void k_ln_out(const float* __restrict__ h, const float* __restrict__ g,
              const float* __restrict__ be, const float* __restrict__ Wo,
              const float* __restrict__ bo, float* __restrict__ out) {
    const int j = threadIdx.x & 63;
    float Wreg[HID];
#pragma unroll
    for (int k = 0; k < HID; ++k) Wreg[k] = Wo[k * OUT_DIM + j];
    const float gj = g[j], bej = be[j], boj = bo[j];
    const int wid = (blockIdx.x * blockDim.x + threadIdx.x) >> 6;
    const int nw  = (gridDim.x * blockDim.x) >> 6;
    for (int v0 = wid * RB; v0 < NN; v0 += nw * RB) {
        float hn[RB];
#pragma unroll
        for (int r = 0; r < RB; ++r) {
            const float x = h[(size_t)(v0 + r) * HID + j];
            float s = x;
#pragma unroll
            for (int m = 32; m >= 1; m >>= 1) s += __shfl_xor(s, m, 64);
            const float mu = s * (1.f / 64.f);
            const float dx = x - mu;
            float vs = dx * dx;
#pragma unroll
            for (int m = 32; m >= 1; m >>= 1) vs += __shfl_xor(vs, m, 64);
            hn[r] = dx * rsqrtf(vs * (1.f / 64.f) + LN_EPS) * gj + bej;
        }
        float acc[RB];
#pragma unroll
        for (int r = 0; r < RB; ++r) acc[r] = boj;
#pragma unroll
        for (int k = 0; k < HID; ++k) {
#pragma unroll
            for (int r = 0; r < RB; ++r)
                acc[r] = fmaf(bcast(hn[r], k), Wreg[k], acc[r]);
        }
#pragma unroll
        for (int r = 0; r < RB; ++r) out[(size_t)(v0 + r) * OUT_DIM + j] = acc[r];
    }
}

extern "C" void kernel_launch(void* const* d_in, const int* in_sizes, int n_in,
                              void* d_out, int out_size, void* d_ws, size_t ws_size,
                              hipStream_t stream) {
    const float* X     = (const float*)d_in[0];
    const int*   src   = (const int*)d_in[1];
    const int*   dst   = (const int*)d_in[2];
    const float* W_in  = (const float*)d_in[3];
    const float* b_in  = (const float*)d_in[4];
    // d_in[5..8]: rewiring MLP params — output is dead, skipped entirely
    const float* W_gat = (const float*)d_in[9];   // (L,64,64)
    const float* a_l   = (const float*)d_in[10];  // (L,4,16)
    const float* a_r   = (const float*)d_in[11];
    const float* b_gat = (const float*)d_in[12];  // (L,64)
    const float* ln_g  = (const float*)d_in[13];
    const float* ln_b  = (const float*)d_in[14];
    const float* W_out = (const float*)d_in[15];
    const float* b_out = (const float*)d_in[16];
    float* out = (float*)d_out;

    float* ws = (float*)d_ws;
    float* hA = ws;                                   // N*64 f32
    float* hB = hA + (size_t)NN * HID;                // N*64 f32
    unsigned* zb32 = (unsigned*)(hB + (size_t)NN * HID);  // N*32 dwords (bf16 pairs)
    float* el = (float*)(zb32 + (size_t)NN * (HID / 2)); // N*4
    float* er = el + (size_t)NN * NH;                 // N*4
    int* rowptr = (int*)(er + (size_t)NN * NH);       // N+1 ints
    int* esrc   = rowptr + NN + 1;                    // E ints
    int* bcnt   = esrc + EE;                          // NB ints
    int* bbase  = bcnt + NB;                          // NB ints
    uintptr_t wp = (uintptr_t)(bbase + NB);
    wp = (wp + 15) & ~(uintptr_t)15;
    uint4* Wb   = (uint4*)wp;                         // 16 KB MFMA-packed W_in
    uint4* Wbg  = Wb + 1024;                          // 3 layers x 640 frags (30 KB)
    int2* bbuf  = (int2*)hB;  // 16.1 MB, aliases hB (dead until first k_gat_dst)

    k_wpack<<<4, 256, 0, stream>>>(W_in, Wb);
    k_wpack_gat<<<dim3(3, NL), 256, 0, stream>>>(W_gat, a_l, a_r, Wbg);
    k_in_gemm<<<(NN + 63) / 64, 256, 0, stream>>>(X, Wb, b_in, hA);

    // bucket-sort CSR by dst (built once, reused for all 3 layers)
    k_zero_bcnt<<<1, 256, 0, stream>>>(bcnt);
    k_bucketize<<<P1_BLOCKS, 256, 0, stream>>>(src, dst, bcnt, bbuf);
    k_bscan<<<1, 256, 0, stream>>>(bcnt, bbase, rowptr);
    k_localcsr<<<NB, 256, 0, stream>>>(bcnt, bbase, bbuf, rowptr, esrc);

    float* hin = hA;
    float* hout = hB;
    for (int l = 0; l < NL; ++l) {
        k_zgemm<<<(NN + 63) / 64, 256, 0, stream>>>(hin, Wbg + (size_t)l * 640,
                                                    zb32, el, er);
        k_gat_dst<<<(NN + 3) / 4, 256, 0, stream>>>(rowptr, esrc, el, er, zb32, hin,
                                                    b_gat + (size_t)l * HID, hout);
        float* t = hin; hin = hout; hout = t;
    }

    k_ln_out<<<1024, 256, 0, stream>>>(hin, ln_g, ln_b, W_out, b_out, out);
}